// Round 26
// baseline (219.276 us; speedup 1.0000x reference)
//
#include <hip/hip_runtime.h>
#include <hip/hip_bf16.h>
#include <math.h>

#define DEV __device__ __forceinline__

typedef __bf16 bf16;
typedef __bf16 bf16x4 __attribute__((ext_vector_type(4)));
typedef __bf16 bf16x8 __attribute__((ext_vector_type(8)));
typedef float f32x4 __attribute__((ext_vector_type(4)));

DEV f32x4 zero4() { f32x4 z; z[0]=0.f; z[1]=0.f; z[2]=0.f; z[3]=0.f; return z; }

DEV void gload_lds16(const bf16* g, bf16* l) {
    __builtin_amdgcn_global_load_lds(
        (const __attribute__((address_space(1))) void*)g,
        (__attribute__((address_space(3))) void*)l, 16, 0, 0);
}

// sigmoid-form GELU: v * sigmoid(1.702 v). 5 VALU ops.
DEV float gelu_f(float v) {
    float e = __expf(-1.702f * v);
    return v * __builtin_amdgcn_rcpf(1.0f + e);
}

DEV f32x4 bmfma(bf16x8 a, bf16x8 b, f32x4 c) {
    return __builtin_amdgcn_mfma_f32_16x16x32_bf16(a, b, c, 0, 0, 0);
}

// ---------------------------------------------------------------------------
// Geometry: B=2, C=192, T=8, H=56, W=56; window (2,7,7) N=98; shift (1,3,3)
// windows: 4*8*8=256 per batch, B_=512; tokens M = 50176
// qkv buffer layout (EPI=5 output): [b_][head][sel(q,k,v)][n=98][d=32];
// Q columns pre-scaled by 32^-0.5 at the qkv epilogue.
// ---------------------------------------------------------------------------

// K00: per-window zero-mask flags.
__global__ __launch_bounds__(256) void prep_flag_k(
    const float* __restrict__ maskm, int* __restrict__ wflag)
{
    __shared__ int f;
    int wib = blockIdx.x;
    if (threadIdx.x == 0) f = 0;
    __syncthreads();
    int any = 0;
    const float* mm = maskm + (size_t)wib*9604;
    for (int i = threadIdx.x; i < 9604; i += 256)
        if (mm[i] != 0.f) any = 1;
    if (any) atomicOr(&f, 1);
    __syncthreads();
    if (threadIdx.x == 0) wflag[wib] = f;
}

// K0 (merged preps): [0,3136) maskB bf16 (skipped for zero-mask windows);
// [3136,3712) weights; [3712,3786) biasF.
__global__ __launch_bounds__(256) void prep_all_k(
    const float* __restrict__ qw, const float* __restrict__ pw,
    const float* __restrict__ f1, const float* __restrict__ f2,
    const float* __restrict__ rpb, const float* __restrict__ maskm,
    bf16* __restrict__ qwt, bf16* __restrict__ pwt,
    bf16* __restrict__ f1t, bf16* __restrict__ f2t,
    float* __restrict__ biasF, bf16* __restrict__ maskB,
    const int* __restrict__ wflag)
{
    int bid = blockIdx.x;
    if (bid < 3136) {
        int i = bid * 256 + threadIdx.x;   // (wib,rt,j,lane)
        if (i >= 256*7*7*64) return;
        int lane = i & 63; int g = i >> 6;
        int j = g % 7; g /= 7; int rt = g % 7; int wib = g / 7;
        if (wflag[wib] == 0) return;       // attn never reads these
        int l15 = lane & 15, lg = lane >> 4;
        int nk = j*16 + l15;
        bf16x4 o;
        #pragma unroll
        for (int r = 0; r < 4; r++) {
            int nq = rt*16 + lg*4 + r; if (nq > 97) nq = 97;
            o[r] = (bf16)((nk < 98) ? maskm[((size_t)wib*98 + nq)*98 + nk] : 0.f);
        }
        *(bf16x4*)&maskB[(size_t)i*4] = o;
    } else if (bid < 3712) {
        int i = (bid - 3136) * 256 + threadIdx.x;
        if (i < 576*192) { int n = i / 192, k = i % 192; qwt[i] = (bf16)qw[(size_t)k*576 + n]; }
        if (i < 192*192) { int n = i / 192, k = i % 192; pwt[i] = (bf16)pw[(size_t)k*192 + n]; }
        if (i < 768*192) { int n = i / 192, k = i % 192; f1t[i] = (bf16)f1[(size_t)k*768 + n]; }
        if (i < 192*768) { int n = i / 768, k = i % 768; f2t[i] = (bf16)f2[(size_t)k*192 + n]; }
    } else {
        int i = (bid - 3712) * 256 + threadIdx.x;   // (head,rt,j,lane)
        if (i >= 6*7*7*64) return;
        int lane = i & 63; int g = i >> 6;
        int j = g % 7; g /= 7; int rt = g % 7; int head = g / 7;
        int l15 = lane & 15, lg = lane >> 4;
        int nk = j*16 + l15;
        f32x4 o;
        #pragma unroll
        for (int r = 0; r < 4; r++) {
            int nq = rt*16 + lg*4 + r; if (nq > 97) nq = 97;
            if (nk < 98) {
                int t1 = nq/49, r1 = nq%49, h1 = r1/7, w1 = r1%7;
                int t2 = nk/49, r2 = nk%49, h2 = r2/7, w2 = r2%7;
                int idx = (t1 - t2 + 1)*169 + (h1 - h2 + 6)*13 + (w1 - w2 + 6);
                o[r] = rpb[idx*6 + head];
            } else {
                o[r] = -1e30f;
            }
        }
        *(f32x4*)&biasF[(size_t)i*4] = o;
    }
}

// K1: LN1 + cyclic shift + window partition. grid = B*T*H = 896.
__global__ __launch_bounds__(256) void ln1_window_k(
    const float* __restrict__ x, const float* __restrict__ g,
    const float* __restrict__ bta, bf16* __restrict__ xw)
{
    __shared__ float tile[56*193];
    __shared__ float mu[56], rs[56];
    int blk = blockIdx.x;
    int bb = blk / 448; int r = blk % 448; int ts = r / 56; int hs = r % 56;
    int t = (ts + 1) & 7;
    int h = hs + 3; if (h >= 56) h -= 56;
    int tid = threadIdx.x;
    const float* xs = x + ((size_t)bb*1536 + t)*3136 + h*56;
    for (int e = tid; e < 192*56; e += 256) {
        int c = e / 56, w = e % 56;
        int wsp = w - 3; if (wsp < 0) wsp += 56;
        tile[wsp*193 + c] = xs[(size_t)c*25088 + w];
    }
    __syncthreads();
    if (tid < 224) {
        int row = tid >> 2, q = tid & 3;
        float s = 0.f, s2 = 0.f;
        for (int c = q*48; c < q*48 + 48; c++) {
            float v = tile[row*193 + c]; s += v; s2 += v*v;
        }
        s  += __shfl_xor(s, 1);  s  += __shfl_xor(s, 2);
        s2 += __shfl_xor(s2, 1); s2 += __shfl_xor(s2, 2);
        if (q == 0) {
            float m = s * (1.0f/192.0f);
            mu[row] = m;
            rs[row] = rsqrtf(s2 * (1.0f/192.0f) - m*m + 1e-5f);
        }
    }
    __syncthreads();
    int tb = ts >> 1, wt = ts & 1;
    int hb = hs / 7, wh = hs % 7;
    for (int e = tid; e < 56*192; e += 256) {
        int wpos = e / 192, c = e % 192;
        float v = (tile[wpos*193 + c] - mu[wpos]) * rs[wpos] * g[c] + bta[c];
        int wb = wpos / 7, ww = wpos % 7;
        int widx = bb*256 + tb*64 + hb*8 + wb;
        int n = wt*49 + wh*7 + ww;
        xw[((size_t)widx*98 + n)*192 + c] = (bf16)v;
    }
}

// Generic bf16 MFMA GEMM: BM/BN templated, XCD-affinity strip swizzle,
// single- (DB=0) or double-buffered (DB=1) staging.
// EPI: 1 f32 direct; 2 gelu bf16 via LDS transpose;
//      4 bf16-resid add + channel-first f32x4 -> d_out;
//      5 bf16 permuted store [b_][head][sel][98][32], Q cols pre-scaled.
template<int BM, int KT, int NT, int BN, int EPI, int DB>
__global__ __launch_bounds__(256) void gemm_k(
    const bf16* __restrict__ A, const bf16* __restrict__ BT,
    const float* __restrict__ bias, const void* __restrict__ resid,
    void* __restrict__ outp)
{
    constexpr int BUFS = DB ? 2 : 1;
    __shared__ bf16 smem[BUFS*BM*64 + BUFS*BN*64];
    bf16* laB = smem;
    bf16* lbB = smem + BUFS*BM*64;
    constexpr int NTILES = NT / BN;
    constexpr int NK = KT / 64;
    constexpr int JT = BN / 32;            // j-tiles per wave
    constexpr int IT = BM / 32;            // i-tiles per wave
    constexpr int WM = BM / 2;             // wave row extent
    constexpr int WN = BN / 2;             // wave col extent
    constexpr int NM = 50176 / BM;         // M strips
    constexpr int SPX = NM / 8;            // strips per XCD (bijective)
    int blk = blockIdx.x;
    int xcd = blk & 7, ix = blk >> 3;
    int m0 = (xcd * SPX + ix / NTILES) * BM;
    int n0 = (ix % NTILES) * BN;
    int tid = threadIdx.x;
    int lane = tid & 63;
    int wv = tid >> 6;
    int wr = wv >> 1, wc = wv & 1;
    int l15 = lane & 15, lg = lane >> 4;

    auto stage = [&](int kt, int buf) {
        int kb = kt * 64;
        #pragma unroll
        for (int t = 0; t < BM/32; t++) {
            int e = t*256 + wv*64 + lane;
            int row = e >> 3, ck = e & 7;
            gload_lds16(&A[(size_t)(m0 + row)*KT + kb + ((ck ^ (row & 7)) << 3)],
                        &laB[buf*BM*64 + (t*256 + wv*64) * 8]);
        }
        #pragma unroll
        for (int t = 0; t < JT; t++) {
            int e = t*256 + wv*64 + lane;
            int row = e >> 3, ck = e & 7;
            gload_lds16(&BT[(size_t)(n0 + row)*KT + kb + ((ck ^ (row & 7)) << 3)],
                        &lbB[buf*BN*64 + (t*256 + wv*64) * 8]);
        }
    };

    f32x4 acc[IT][JT];
    #pragma unroll
    for (int i = 0; i < IT; i++)
        #pragma unroll
        for (int j = 0; j < JT; j++) acc[i][j] = zero4();

    auto compute = [&](int cur) {
        const bf16* lab = laB + cur*BM*64;
        const bf16* lbb = lbB + cur*BN*64;
        #pragma unroll
        for (int ks = 0; ks < 64; ks += 32) {
            int lc = (ks >> 3) + lg;
            bf16x8 af[IT], bfr[JT];
            #pragma unroll
            for (int i = 0; i < IT; i++) {
                int ri = wr*WM + i*16 + l15;
                af[i] = *(const bf16x8*)&lab[ri*64 + ((lc ^ (ri & 7)) << 3)];
            }
            #pragma unroll
            for (int j = 0; j < JT; j++) {
                int rj = wc*WN + j*16 + l15;
                bfr[j] = *(const bf16x8*)&lbb[rj*64 + ((lc ^ (rj & 7)) << 3)];
            }
            #pragma unroll
            for (int i = 0; i < IT; i++)
                #pragma unroll
                for (int j = 0; j < JT; j++)
                    acc[i][j] = bmfma(af[i], bfr[j], acc[i][j]);
        }
    };

    if constexpr (DB) {
        stage(0, 0);
        __syncthreads();
        for (int kt = 0; kt < NK; kt++) {
            int cur = kt & 1;
            if (kt + 1 < NK) stage(kt + 1, cur ^ 1);
            compute(cur);
            __syncthreads();
        }
    } else {
        for (int kt = 0; kt < NK; kt++) {
            stage(kt, 0);
            __syncthreads();
            compute(0);
            __syncthreads();
        }
    }

    if constexpr (EPI == 4) {
        const bf16* rs = (const bf16*)resid;
        #pragma unroll
        for (int i = 0; i < IT; i++) {
            #pragma unroll
            for (int j = 0; j < JT; j++) {
                int row0 = m0 + wr*WM + i*16 + lg*4;
                int col = n0 + wc*WN + j*16 + l15;
                f32x4 o;
                #pragma unroll
                for (int r = 0; r < 4; r++)
                    o[r] = acc[i][j][r] + bias[col] + (float)rs[(size_t)(row0 + r)*NT + col];
                int bb2 = row0 >= 25088;
                size_t off = (size_t)bb2*192*25088 + (size_t)col*25088 + (row0 - bb2*25088);
                *(f32x4*)&((float*)outp)[off] = o;
            }
        }
    } else if constexpr (EPI == 5) {
        #pragma unroll
        for (int i = 0; i < IT; i++) {
            #pragma unroll
            for (int j = 0; j < JT; j++) {
                int col = n0 + wc*WN + j*16 + l15;
                int sel = col / 192, hd = (col % 192) >> 5, d = col & 31;
                float bv = bias[col];
                float sc = (sel == 0) ? 0.17677669529663687f : 1.0f;
                #pragma unroll
                for (int r = 0; r < 4; r++) {
                    int row = m0 + wr*WM + i*16 + lg*4 + r;
                    int b_ = row / 98, n = row - b_*98;
                    size_t dst = (((size_t)b_*6 + hd)*3 + sel)*3136 + n*32 + d;
                    ((bf16*)outp)[dst] = (bf16)((acc[i][j][r] + bv) * sc);
                }
            }
        }
    } else if constexpr (EPI == 1) {
        #pragma unroll
        for (int i = 0; i < IT; i++) {
            #pragma unroll
            for (int j = 0; j < JT; j++) {
                #pragma unroll
                for (int r = 0; r < 4; r++) {
                    int row = m0 + wr*WM + i*16 + lg*4 + r;
                    int col = n0 + wc*WN + j*16 + l15;
                    ((float*)outp)[(size_t)row*NT + col] = acc[i][j][r] + bias[col];
                }
            }
        }
    } else {
        // EPI==2: gelu -> bf16 LDS transpose ([BM][72]) -> 16B stores.
        bf16* fs = smem;
        #pragma unroll
        for (int i = 0; i < IT; i++) {
            #pragma unroll
            for (int j = 0; j < JT; j++) {
                int colw = wc*WN + j*16 + l15;
                float bv = bias[n0 + colw];
                #pragma unroll
                for (int r = 0; r < 4; r++) {
                    int lr = wr*WM + i*16 + lg*4 + r;
                    fs[lr*72 + colw] = (bf16)gelu_f(acc[i][j][r] + bv);
                }
            }
        }
        __syncthreads();
        {
            constexpr int EPT = BM / 4;        // elems per thread
            constexpr int TPR = 64 / EPT;      // threads per row
            int lr = tid / TPR, c0 = (tid % TPR) * EPT;
            size_t gbase = (size_t)(m0 + lr)*NT + n0 + c0;
            #pragma unroll
            for (int k = 0; k < EPT/8; k++) {
                bf16x8 o = *(const bf16x8*)&fs[lr*72 + c0 + k*8];
                *(bf16x8*)&((bf16*)outp)[gbase + k*8] = o;
            }
        }
    }
}

// K3: attention, one block per (WINDOW, HEAD). grid 3072, block 256 (4 waves).
// Wave wv handles rt in {2wv, 2wv+1} (wave 3: rt 6 only). Q pre-scaled at
// qkv epilogue; zero-mask windows (wflag==0) skip mask loads entirely;
// mask table is bf16. VT staged with clamped source rows.
__global__ __launch_bounds__(256) void attn_k(
    const bf16* __restrict__ qkv, const float* __restrict__ biasF,
    const bf16* __restrict__ maskB, const int* __restrict__ wflag,
    bf16* __restrict__ aout)
{
    __shared__ bf16 VT[32*128];
    __shared__ bf16 Pl[4*16*136];
    int blk = blockIdx.x;
    int t8 = (blk & 7) * 384 + (blk >> 3);
    int b_ = t8 / 6, head = t8 % 6;
    int tid = threadIdx.x, lane = tid & 63, wv = tid >> 6;
    int l15 = lane & 15, lg = (lane >> 4) & 3;
    int wib = b_ & 255;
    const bf16* base = qkv + (size_t)(b_*6 + head)*3*3136;
    const int hasmask = wflag[wib];

    {
        // Pl pad cols (112..127) zero for 4 wave-buffers + full VT stage
        unsigned int* pz = (unsigned int*)Pl;
        for (int e = tid; e < 512; e += 256) {
            int w2 = e >> 7, rem = e & 127;
            int row = rem >> 3, cp = rem & 7;
            pz[(w2*16 + row)*68 + 56 + cp] = 0u;
        }
        int dq = tid >> 6;               // d-octet 0..3
        int kl = tid & 63;
        const bf16* vbase = base + 2*3136 + dq*8;
        #pragma unroll
        for (int kr = 0; kr < 2; kr++) {
            int k = kr*64 + kl;
            int ks = k > 97 ? 97 : k;
            bf16x8 v8 = *(const bf16x8*)&vbase[ks*32];
            #pragma unroll
            for (int j = 0; j < 8; j++)
                VT[(dq*8 + j)*128 + (k ^ (j << 3))] = v8[j];
        }
    }
    __syncthreads();

    bf16x8 kfr[7];
    #pragma unroll
    for (int j = 0; j < 7; j++) {
        int krow = j*16 + l15; if (krow > 97) krow = 97;
        kfr[j] = *(const bf16x8*)&base[3136 + krow*32 + lg*8];
    }

    bf16* Pw = Pl + wv*16*136;
    const int rt0 = wv*2;
    const int rt1 = (wv*2 + 2 < 7) ? wv*2 + 2 : 7;

    auto loadQ = [&](int rt) {
        int qrow = rt*16 + l15; if (qrow > 97) qrow = 97;
        return *(const bf16x8*)&base[qrow*32 + lg*8];
    };
    bf16x8 qf = loadQ(rt0);

    #pragma unroll 1
    for (int rt = rt0; rt < rt1; rt++) {
        bf16x8 qnext = qf;
        if (rt + 1 < rt1) qnext = loadQ(rt + 1);
        f32x4 sacc[7];
        #pragma unroll
        for (int j = 0; j < 7; j++) sacc[j] = zero4();
        #pragma unroll
        for (int j = 0; j < 7; j++)
            sacc[j] = bmfma(qf, kfr[j], sacc[j]);
        {
            const float* bfp = biasF + ((size_t)(head*7 + rt)*7)*256 + lane*4;
            #pragma unroll
            for (int j = 0; j < 7; j++) {
                f32x4 bv = *(const f32x4*)&bfp[j*256];
                sacc[j] = sacc[j] + bv;
            }
            if (hasmask) {
                const bf16* mfp = maskB + ((size_t)(wib*7 + rt)*7)*256 + lane*4;
                #pragma unroll
                for (int j = 0; j < 7; j++) {
                    bf16x4 mv = *(const bf16x4*)&mfp[j*256];
                    #pragma unroll
                    for (int r = 0; r < 4; r++) sacc[j][r] += (float)mv[r];
                }
            }
            f32x4 m4 = sacc[0];
            #pragma unroll
            for (int j = 1; j < 7; j++) {
                #pragma unroll
                for (int r = 0; r < 4; r++) m4[r] = fmaxf(m4[r], sacc[j][r]);
            }
            #pragma unroll
            for (int d = 1; d < 16; d <<= 1) {
                #pragma unroll
                for (int r = 0; r < 4; r++) m4[r] = fmaxf(m4[r], __shfl_xor(m4[r], d));
            }
            f32x4 s4 = zero4();
            #pragma unroll
            for (int j = 0; j < 7; j++) {
                #pragma unroll
                for (int r = 0; r < 4; r++) sacc[j][r] = __expf(sacc[j][r] - m4[r]);
                s4 += sacc[j];
            }
            #pragma unroll
            for (int d = 1; d < 16; d <<= 1) {
                #pragma unroll
                for (int r = 0; r < 4; r++) s4[r] += __shfl_xor(s4[r], d);
            }
            f32x4 inv4;
            #pragma unroll
            for (int r = 0; r < 4; r++) inv4[r] = 1.0f / s4[r];
            #pragma unroll
            for (int j = 0; j < 7; j++)
                #pragma unroll
                for (int r = 0; r < 4; r++)
                    Pw[(lg*4 + r)*136 + j*16 + l15] = (bf16)(sacc[j][r]*inv4[r]);
        }
        #pragma unroll
        for (int dt = 0; dt < 2; dt++) {
            int dl = dt*16 + l15;
            int xr = (dl & 7) << 3;
            f32x4 oacc = zero4();
            #pragma unroll
            for (int kc = 0; kc < 4; kc++) {
                bf16x8 pf = *(const bf16x8*)&Pw[l15*136 + kc*32 + lg*8];
                bf16x8 vf = *(const bf16x8*)&VT[dl*128 + ((kc*32 + lg*8) ^ xr)];
                oacc = bmfma(pf, vf, oacc);
            }
            #pragma unroll
            for (int r = 0; r < 4; r++) {
                int row = rt*16 + lg*4 + r;
                if (row < 98)
                    aout[((size_t)b_*98 + row)*192 + head*32 + dt*16 + l15] = (bf16)oacc[r];
            }
        }
        qf = qnext;
    }
}

// K5: window reverse + roll-back + residual(x) + LN2. grid 896.
// x1 out bf16 (LN2 stats still f32 from the LDS tile).
__global__ __launch_bounds__(256) void rev_res_ln2_k(
    const float* __restrict__ x, const float* __restrict__ pw,
    const float* __restrict__ g2, const float* __restrict__ b2,
    bf16* __restrict__ x1, bf16* __restrict__ xn2)
{
    __shared__ float tile[56*193];
    __shared__ float mu[56], rs[56];
    int blk = blockIdx.x;
    int bb = blk / 448; int r = blk % 448; int t = r / 56; int h = r % 56;
    int ts = (t + 7) & 7;
    int hs = h - 3; if (hs < 0) hs += 56;
    int tid = threadIdx.x;
    const float* xs = x + ((size_t)bb*1536 + t)*3136 + h*56;
    for (int e = tid; e < 192*56; e += 256) {
        int c = e / 56, w = e % 56;
        tile[w*193 + c] = xs[(size_t)c*25088 + w];
    }
    __syncthreads();
    int tb = ts >> 1, wt = ts & 1, hb = hs / 7, wh = hs % 7;
    for (int e = tid; e < 56*192; e += 256) {
        int w = e / 192, c = e % 192;
        int wsp = w - 3; if (wsp < 0) wsp += 56;
        int wb = wsp / 7, ww = wsp % 7;
        size_t tok = (size_t)(bb*256 + tb*64 + hb*8 + wb)*98 + wt*49 + wh*7 + ww;
        tile[w*193 + c] += pw[tok*192 + c];
    }
    __syncthreads();
    if (tid < 224) {
        int row = tid >> 2, q = tid & 3;
        float s = 0.f, s2 = 0.f;
        for (int c = q*48; c < q*48 + 48; c++) {
            float v = tile[row*193 + c]; s += v; s2 += v*v;
        }
        s  += __shfl_xor(s, 1);  s  += __shfl_xor(s, 2);
        s2 += __shfl_xor(s2, 1); s2 += __shfl_xor(s2, 2);
        if (q == 0) {
            float m = s * (1.0f/192.0f);
            mu[row] = m;
            rs[row] = rsqrtf(s2 * (1.0f/192.0f) - m*m + 1e-5f);
        }
    }
    __syncthreads();
    size_t tok0 = ((size_t)(bb*8 + t)*56 + h)*56;
    for (int e = tid; e < 56*192; e += 256) {
        int w = e / 192, c = e % 192;
        float v = tile[w*193 + c];
        x1[(tok0 + w)*192 + c] = (bf16)v;
        xn2[(tok0 + w)*192 + c] = (bf16)((v - mu[w]) * rs[w] * g2[c] + b2[c]);
    }
}

// ---------------------------------------------------------------------------
extern "C" void kernel_launch(void* const* d_in, const int* in_sizes, int n_in,
                              void* d_out, int out_size, void* d_ws, size_t ws_size,
                              hipStream_t stream)
{
    const float* x     = (const float*)d_in[0];
    const float* maskm = (const float*)d_in[1];
    const float* n1g   = (const float*)d_in[2];
    const float* n1b   = (const float*)d_in[3];
    const float* qkvw  = (const float*)d_in[4];
    const float* qkvb  = (const float*)d_in[5];
    const float* projw = (const float*)d_in[6];
    const float* projb = (const float*)d_in[7];
    const float* rpb   = (const float*)d_in[8];
    const float* n2g   = (const float*)d_in[9];
    const float* n2b   = (const float*)d_in[10];
    const float* f1w   = (const float*)d_in[11];
    const float* f1b   = (const float*)d_in[12];
    const float* f2w   = (const float*)d_in[13];
    const float* f2b   = (const float*)d_in[14];

    char* ws = (char*)d_ws;
    int*   wflag   = (int*)(ws + 0);            // 1024
    bf16*  qkv_wt  = (bf16*)(ws + 1024);        // 221184
    bf16*  proj_wt = (bf16*)(ws + 222208);      // 73728
    bf16*  fc1_wt  = (bf16*)(ws + 295936);      // 294912
    bf16*  fc2_wt  = (bf16*)(ws + 590848);      // 294912
    float* biasF   = (float*)(ws + 885760);     // 294912
    // region A: xw (bf16, 19.27MB) -> reused as attn_out
    bf16* xw   = (bf16*)(ws + 1180672);
    bf16* aout = xw;
    // region B: qkv (bf16, 57.8MB, permuted) -> reused as proj-out f32
    char* Bp = ws + 1180672 + 19267584;
    bf16*  qkv  = (bf16*)Bp;
    float* pwin = (float*)Bp;
    // region C: x1 bf16; region D: xn2 bf16; region E: h1 bf16 / maskB bf16
    char* Cp = Bp + 57802752;
    bf16*  x1  = (bf16*)Cp;
    bf16*  xn2 = (bf16*)(Cp + 19267584);
    bf16*  h1  = (bf16*)(Cp + 19267584 + 19267584);
    // maskB (6.4MB bf16) aliases h1: read only during attn, h1 written by
    // fc1 strictly after attn completes.
    bf16*  maskB = (bf16*)(Cp + 19267584 + 19267584);

    prep_flag_k<<<256, 256, 0, stream>>>(maskm, wflag);
    prep_all_k<<<3786, 256, 0, stream>>>(qkvw, projw, f1w, f2w, rpb, maskm,
                                         qkv_wt, proj_wt, fc1_wt, fc2_wt,
                                         biasF, maskB, wflag);
    ln1_window_k<<<896, 256, 0, stream>>>(x, n1g, n1b, xw);
    gemm_k<64, 192, 576, 192, 5, 0><<<784*3, 256, 0, stream>>>(xw, qkv_wt, qkvb, nullptr, qkv);
    attn_k<<<3072, 256, 0, stream>>>(qkv, biasF, maskB, wflag, aout);
    gemm_k<64, 192, 192, 64, 1, 0><<<784*3, 256, 0, stream>>>(aout, proj_wt, projb, nullptr, pwin);
    rev_res_ln2_k<<<896, 256, 0, stream>>>(x, pwin, n2g, n2b, x1, xn2);
    gemm_k<64, 192, 768, 64, 2, 0><<<784*12, 256, 0, stream>>>(xn2, fc1_wt, f1b, nullptr, h1);
    gemm_k<128, 768, 192, 64, 4, 1><<<392*3, 256, 0, stream>>>(h1, fc2_wt, f2b, x1, (float*)d_out);
}

// Round 27
// 208.587 us; speedup vs baseline: 1.0512x; 1.0512x over previous
//
#include <hip/hip_runtime.h>
#include <hip/hip_bf16.h>
#include <math.h>

#define DEV __device__ __forceinline__

typedef __bf16 bf16;
typedef __bf16 bf16x8 __attribute__((ext_vector_type(8)));
typedef float f32x4 __attribute__((ext_vector_type(4)));

DEV f32x4 zero4() { f32x4 z; z[0]=0.f; z[1]=0.f; z[2]=0.f; z[3]=0.f; return z; }

DEV void gload_lds16(const bf16* g, bf16* l) {
    __builtin_amdgcn_global_load_lds(
        (const __attribute__((address_space(1))) void*)g,
        (__attribute__((address_space(3))) void*)l, 16, 0, 0);
}

// sigmoid-form GELU: v * sigmoid(1.702 v). 5 VALU ops.
DEV float gelu_f(float v) {
    float e = __expf(-1.702f * v);
    return v * __builtin_amdgcn_rcpf(1.0f + e);
}

DEV f32x4 bmfma(bf16x8 a, bf16x8 b, f32x4 c) {
    return __builtin_amdgcn_mfma_f32_16x16x32_bf16(a, b, c, 0, 0, 0);
}

// ---------------------------------------------------------------------------
// Geometry: B=2, C=192, T=8, H=56, W=56; window (2,7,7) N=98; shift (1,3,3)
// windows: 4*8*8=256 per batch, B_=512; tokens M = 50176
// qkv buffer layout (EPI=5 output): [b_][head][sel(q,k,v)][n=98][d=32]
// ---------------------------------------------------------------------------

// K0 (merged preps): blocks [0,3136) -> maskF, [3136,3712) -> weights,
// [3712,3786) -> biasF.
__global__ __launch_bounds__(256) void prep_all_k(
    const float* __restrict__ qw, const float* __restrict__ pw,
    const float* __restrict__ f1, const float* __restrict__ f2,
    const float* __restrict__ rpb, const float* __restrict__ maskm,
    bf16* __restrict__ qwt, bf16* __restrict__ pwt,
    bf16* __restrict__ f1t, bf16* __restrict__ f2t,
    float* __restrict__ biasF, float* __restrict__ maskF)
{
    int bid = blockIdx.x;
    if (bid < 3136) {
        int i = bid * 256 + threadIdx.x;   // (wib,rt,j,lane)
        if (i >= 256*7*7*64) return;
        int lane = i & 63; int g = i >> 6;
        int j = g % 7; g /= 7; int rt = g % 7; int wib = g / 7;
        int l15 = lane & 15, lg = lane >> 4;
        int nk = j*16 + l15;
        f32x4 o;
        #pragma unroll
        for (int r = 0; r < 4; r++) {
            int nq = rt*16 + lg*4 + r; if (nq > 97) nq = 97;
            o[r] = (nk < 98) ? maskm[((size_t)wib*98 + nq)*98 + nk] : 0.f;
        }
        *(f32x4*)&maskF[(size_t)i*4] = o;
    } else if (bid < 3712) {
        int i = (bid - 3136) * 256 + threadIdx.x;
        if (i < 576*192) { int n = i / 192, k = i % 192; qwt[i] = (bf16)qw[(size_t)k*576 + n]; }
        if (i < 192*192) { int n = i / 192, k = i % 192; pwt[i] = (bf16)pw[(size_t)k*192 + n]; }
        if (i < 768*192) { int n = i / 192, k = i % 192; f1t[i] = (bf16)f1[(size_t)k*768 + n]; }
        if (i < 192*768) { int n = i / 768, k = i % 768; f2t[i] = (bf16)f2[(size_t)k*192 + n]; }
    } else {
        int i = (bid - 3712) * 256 + threadIdx.x;   // (head,rt,j,lane)
        if (i >= 6*7*7*64) return;
        int lane = i & 63; int g = i >> 6;
        int j = g % 7; g /= 7; int rt = g % 7; int head = g / 7;
        int l15 = lane & 15, lg = lane >> 4;
        int nk = j*16 + l15;
        f32x4 o;
        #pragma unroll
        for (int r = 0; r < 4; r++) {
            int nq = rt*16 + lg*4 + r; if (nq > 97) nq = 97;
            if (nk < 98) {
                int t1 = nq/49, r1 = nq%49, h1 = r1/7, w1 = r1%7;
                int t2 = nk/49, r2 = nk%49, h2 = r2/7, w2 = r2%7;
                int idx = (t1 - t2 + 1)*169 + (h1 - h2 + 6)*13 + (w1 - w2 + 6);
                o[r] = rpb[idx*6 + head];
            } else {
                o[r] = -1e30f;
            }
        }
        *(f32x4*)&biasF[(size_t)i*4] = o;
    }
}

// K1: LN1 + cyclic shift + window partition. grid = B*T*H*2 = 1792
// (half-width split: 28 tokens/block, 21.6KB LDS -> ~7 blocks/CU).
__global__ __launch_bounds__(256) void ln1_window_k(
    const float* __restrict__ x, const float* __restrict__ g,
    const float* __restrict__ bta, bf16* __restrict__ xw)
{
    __shared__ float tile[28*193];
    __shared__ float mu[28], rs[28];
    int blk = blockIdx.x;
    int bb = blk / 896; int r = blk % 896;
    int ts = r / 112; int rem = r % 112;
    int hs = rem >> 1, half = rem & 1;
    int t = (ts + 1) & 7;
    int h = hs + 3; if (h >= 56) h -= 56;
    int tid = threadIdx.x;
    const float* xs = x + ((size_t)bb*1536 + t)*3136 + h*56;
    for (int e = tid; e < 192*28; e += 256) {
        int c = e / 28, wi = e % 28;
        int w = half*28 + wi + 3; if (w >= 56) w -= 56;
        tile[wi*193 + c] = xs[(size_t)c*25088 + w];
    }
    __syncthreads();
    if (tid < 112) {
        int row = tid >> 2, q = tid & 3;
        float s = 0.f, s2 = 0.f;
        for (int c = q*48; c < q*48 + 48; c++) {
            float v = tile[row*193 + c]; s += v; s2 += v*v;
        }
        s  += __shfl_xor(s, 1);  s  += __shfl_xor(s, 2);
        s2 += __shfl_xor(s2, 1); s2 += __shfl_xor(s2, 2);
        if (q == 0) {
            float m = s * (1.0f/192.0f);
            mu[row] = m;
            rs[row] = rsqrtf(s2 * (1.0f/192.0f) - m*m + 1e-5f);
        }
    }
    __syncthreads();
    int tb = ts >> 1, wt = ts & 1;
    int hb = hs / 7, wh = hs % 7;
    for (int e = tid; e < 28*192; e += 256) {
        int wi = e / 192, c = e % 192;
        int wsp = half*28 + wi;
        float v = (tile[wi*193 + c] - mu[wi]) * rs[wi] * g[c] + bta[c];
        int wb = wsp / 7, ww = wsp % 7;
        int widx = bb*256 + tb*64 + hb*8 + wb;
        int n = wt*49 + wh*7 + ww;
        xw[((size_t)widx*98 + n)*192 + c] = (bf16)v;
    }
}

// Generic bf16 MFMA GEMM: BM/BN templated, XCD-affinity strip swizzle,
// single- (DB=0) or double-buffered (DB=1) staging.
// EPI: 1 f32 direct; 2 gelu bf16 via LDS transpose;
//      4 bf16-resid add + channel-first f32x4 -> d_out;
//      5 bf16 permuted store [b_][head][sel][98][32] (attn-coalesced).
template<int BM, int KT, int NT, int BN, int EPI, int DB>
__global__ __launch_bounds__(256) void gemm_k(
    const bf16* __restrict__ A, const bf16* __restrict__ BT,
    const float* __restrict__ bias, const void* __restrict__ resid,
    void* __restrict__ outp)
{
    constexpr int BUFS = DB ? 2 : 1;
    __shared__ bf16 smem[BUFS*BM*64 + BUFS*BN*64];
    bf16* laB = smem;
    bf16* lbB = smem + BUFS*BM*64;
    constexpr int NTILES = NT / BN;
    constexpr int NK = KT / 64;
    constexpr int JT = BN / 32;            // j-tiles per wave
    constexpr int IT = BM / 32;            // i-tiles per wave
    constexpr int WM = BM / 2;             // wave row extent
    constexpr int WN = BN / 2;             // wave col extent
    constexpr int NM = 50176 / BM;         // M strips
    constexpr int SPX = NM / 8;            // strips per XCD (bijective)
    int blk = blockIdx.x;
    int xcd = blk & 7, ix = blk >> 3;
    int m0 = (xcd * SPX + ix / NTILES) * BM;
    int n0 = (ix % NTILES) * BN;
    int tid = threadIdx.x;
    int lane = tid & 63;
    int wv = tid >> 6;
    int wr = wv >> 1, wc = wv & 1;
    int l15 = lane & 15, lg = lane >> 4;

    auto stage = [&](int kt, int buf) {
        int kb = kt * 64;
        #pragma unroll
        for (int t = 0; t < BM/32; t++) {
            int e = t*256 + wv*64 + lane;
            int row = e >> 3, ck = e & 7;
            gload_lds16(&A[(size_t)(m0 + row)*KT + kb + ((ck ^ (row & 7)) << 3)],
                        &laB[buf*BM*64 + (t*256 + wv*64) * 8]);
        }
        #pragma unroll
        for (int t = 0; t < JT; t++) {
            int e = t*256 + wv*64 + lane;
            int row = e >> 3, ck = e & 7;
            gload_lds16(&BT[(size_t)(n0 + row)*KT + kb + ((ck ^ (row & 7)) << 3)],
                        &lbB[buf*BN*64 + (t*256 + wv*64) * 8]);
        }
    };

    f32x4 acc[IT][JT];
    #pragma unroll
    for (int i = 0; i < IT; i++)
        #pragma unroll
        for (int j = 0; j < JT; j++) acc[i][j] = zero4();

    auto compute = [&](int cur) {
        const bf16* lab = laB + cur*BM*64;
        const bf16* lbb = lbB + cur*BN*64;
        #pragma unroll
        for (int ks = 0; ks < 64; ks += 32) {
            int lc = (ks >> 3) + lg;
            bf16x8 af[IT], bfr[JT];
            #pragma unroll
            for (int i = 0; i < IT; i++) {
                int ri = wr*WM + i*16 + l15;
                af[i] = *(const bf16x8*)&lab[ri*64 + ((lc ^ (ri & 7)) << 3)];
            }
            #pragma unroll
            for (int j = 0; j < JT; j++) {
                int rj = wc*WN + j*16 + l15;
                bfr[j] = *(const bf16x8*)&lbb[rj*64 + ((lc ^ (rj & 7)) << 3)];
            }
            #pragma unroll
            for (int i = 0; i < IT; i++)
                #pragma unroll
                for (int j = 0; j < JT; j++)
                    acc[i][j] = bmfma(af[i], bfr[j], acc[i][j]);
        }
    };

    if constexpr (DB) {
        stage(0, 0);
        __syncthreads();
        for (int kt = 0; kt < NK; kt++) {
            int cur = kt & 1;
            if (kt + 1 < NK) stage(kt + 1, cur ^ 1);
            compute(cur);
            __syncthreads();
        }
    } else {
        for (int kt = 0; kt < NK; kt++) {
            stage(kt, 0);
            __syncthreads();
            compute(0);
            __syncthreads();
        }
    }

    if constexpr (EPI == 4) {
        const bf16* rs = (const bf16*)resid;
        #pragma unroll
        for (int i = 0; i < IT; i++) {
            #pragma unroll
            for (int j = 0; j < JT; j++) {
                int row0 = m0 + wr*WM + i*16 + lg*4;
                int col = n0 + wc*WN + j*16 + l15;
                f32x4 o;
                #pragma unroll
                for (int r = 0; r < 4; r++)
                    o[r] = acc[i][j][r] + bias[col] + (float)rs[(size_t)(row0 + r)*NT + col];
                int bb2 = row0 >= 25088;
                size_t off = (size_t)bb2*192*25088 + (size_t)col*25088 + (row0 - bb2*25088);
                *(f32x4*)&((float*)outp)[off] = o;
            }
        }
    } else if constexpr (EPI == 5) {
        #pragma unroll
        for (int i = 0; i < IT; i++) {
            #pragma unroll
            for (int j = 0; j < JT; j++) {
                int col = n0 + wc*WN + j*16 + l15;
                int sel = col / 192, hd = (col % 192) >> 5, d = col & 31;
                float bv = bias[col];
                #pragma unroll
                for (int r = 0; r < 4; r++) {
                    int row = m0 + wr*WM + i*16 + lg*4 + r;
                    int b_ = row / 98, n = row - b_*98;
                    size_t dst = (((size_t)b_*6 + hd)*3 + sel)*3136 + n*32 + d;
                    ((bf16*)outp)[dst] = (bf16)(acc[i][j][r] + bv);
                }
            }
        }
    } else if constexpr (EPI == 1) {
        #pragma unroll
        for (int i = 0; i < IT; i++) {
            #pragma unroll
            for (int j = 0; j < JT; j++) {
                #pragma unroll
                for (int r = 0; r < 4; r++) {
                    int row = m0 + wr*WM + i*16 + lg*4 + r;
                    int col = n0 + wc*WN + j*16 + l15;
                    ((float*)outp)[(size_t)row*NT + col] = acc[i][j][r] + bias[col];
                }
            }
        }
    } else {
        // EPI==2: gelu -> bf16 LDS transpose ([BM][72]) -> 16B stores.
        bf16* fs = smem;
        #pragma unroll
        for (int i = 0; i < IT; i++) {
            #pragma unroll
            for (int j = 0; j < JT; j++) {
                int colw = wc*WN + j*16 + l15;
                float bv = bias[n0 + colw];
                #pragma unroll
                for (int r = 0; r < 4; r++) {
                    int lr = wr*WM + i*16 + lg*4 + r;
                    fs[lr*72 + colw] = (bf16)gelu_f(acc[i][j][r] + bv);
                }
            }
        }
        __syncthreads();
        {
            constexpr int EPT = BM / 4;        // elems per thread
            constexpr int TPR = 64 / EPT;      // threads per row
            int lr = tid / TPR, c0 = (tid % TPR) * EPT;
            size_t gbase = (size_t)(m0 + lr)*NT + n0 + c0;
            #pragma unroll
            for (int k = 0; k < EPT/8; k++) {
                bf16x8 o = *(const bf16x8*)&fs[lr*72 + c0 + k*8];
                *(bf16x8*)&((bf16*)outp)[gbase + k*8] = o;
            }
        }
    }
}

// K3: attention, one block per (WINDOW, HEAD). grid 3072, block 256 (4 waves).
// Wave wv handles rt in {2wv, 2wv+1} (wave 3: rt 6 only). Pl has 4 per-wave
// buffers (LDS 25.4KB). VT staged with clamped source rows (keys>=98 hold
// V[97]; their P is exactly 0 via the -1e30 bias).
__global__ __launch_bounds__(256) void attn_k(
    const bf16* __restrict__ qkv, const float* __restrict__ biasF,
    const float* __restrict__ maskF, bf16* __restrict__ aout)
{
    __shared__ bf16 VT[32*128];
    __shared__ bf16 Pl[4*16*136];
    int blk = blockIdx.x;
    int t8 = (blk & 7) * 384 + (blk >> 3);
    int b_ = t8 / 6, head = t8 % 6;
    int tid = threadIdx.x, lane = tid & 63, wv = tid >> 6;
    int l15 = lane & 15, lg = (lane >> 4) & 3;
    int wib = b_ & 255;
    const bf16* base = qkv + (size_t)(b_*6 + head)*3*3136;

    {
        // Pl pad cols (112..127) zero for 4 wave-buffers + full VT stage
        unsigned int* pz = (unsigned int*)Pl;
        for (int e = tid; e < 512; e += 256) {
            int w2 = e >> 7, rem = e & 127;
            int row = rem >> 3, cp = rem & 7;
            pz[(w2*16 + row)*68 + 56 + cp] = 0u;
        }
        int dq = tid >> 6;               // d-octet 0..3
        int kl = tid & 63;
        const bf16* vbase = base + 2*3136 + dq*8;
        #pragma unroll
        for (int kr = 0; kr < 2; kr++) {
            int k = kr*64 + kl;
            int ks = k > 97 ? 97 : k;
            bf16x8 v8 = *(const bf16x8*)&vbase[ks*32];
            #pragma unroll
            for (int j = 0; j < 8; j++)
                VT[(dq*8 + j)*128 + (k ^ (j << 3))] = v8[j];
        }
    }
    __syncthreads();

    bf16x8 kfr[7];
    #pragma unroll
    for (int j = 0; j < 7; j++) {
        int krow = j*16 + l15; if (krow > 97) krow = 97;
        kfr[j] = *(const bf16x8*)&base[3136 + krow*32 + lg*8];
    }

    const float scale = 0.17677669529663687f;
    bf16* Pw = Pl + wv*16*136;
    const int rt0 = wv*2;
    const int rt1 = (wv*2 + 2 < 7) ? wv*2 + 2 : 7;

    auto loadQ = [&](int rt) {
        int qrow = rt*16 + l15; if (qrow > 97) qrow = 97;
        return *(const bf16x8*)&base[qrow*32 + lg*8];
    };
    bf16x8 qf = loadQ(rt0);

    #pragma unroll 1
    for (int rt = rt0; rt < rt1; rt++) {
        bf16x8 qnext = qf;
        if (rt + 1 < rt1) qnext = loadQ(rt + 1);
        f32x4 sacc[7];
        #pragma unroll
        for (int j = 0; j < 7; j++) sacc[j] = zero4();
        #pragma unroll
        for (int j = 0; j < 7; j++)
            sacc[j] = bmfma(qf, kfr[j], sacc[j]);
        {
            const float* bfp = biasF + ((size_t)(head*7 + rt)*7)*256 + lane*4;
            const float* mfp = maskF + ((size_t)(wib*7 + rt)*7)*256 + lane*4;
            #pragma unroll
            for (int j = 0; j < 7; j++) {
                f32x4 bv = *(const f32x4*)&bfp[j*256];
                f32x4 mv = *(const f32x4*)&mfp[j*256];
                sacc[j] = sacc[j]*scale + bv + mv;
            }
            f32x4 m4 = sacc[0];
            #pragma unroll
            for (int j = 1; j < 7; j++) {
                #pragma unroll
                for (int r = 0; r < 4; r++) m4[r] = fmaxf(m4[r], sacc[j][r]);
            }
            #pragma unroll
            for (int d = 1; d < 16; d <<= 1) {
                #pragma unroll
                for (int r = 0; r < 4; r++) m4[r] = fmaxf(m4[r], __shfl_xor(m4[r], d));
            }
            f32x4 s4 = zero4();
            #pragma unroll
            for (int j = 0; j < 7; j++) {
                #pragma unroll
                for (int r = 0; r < 4; r++) sacc[j][r] = __expf(sacc[j][r] - m4[r]);
                s4 += sacc[j];
            }
            #pragma unroll
            for (int d = 1; d < 16; d <<= 1) {
                #pragma unroll
                for (int r = 0; r < 4; r++) s4[r] += __shfl_xor(s4[r], d);
            }
            f32x4 inv4;
            #pragma unroll
            for (int r = 0; r < 4; r++) inv4[r] = 1.0f / s4[r];
            #pragma unroll
            for (int j = 0; j < 7; j++)
                #pragma unroll
                for (int r = 0; r < 4; r++)
                    Pw[(lg*4 + r)*136 + j*16 + l15] = (bf16)(sacc[j][r]*inv4[r]);
        }
        #pragma unroll
        for (int dt = 0; dt < 2; dt++) {
            int dl = dt*16 + l15;
            int xr = (dl & 7) << 3;
            f32x4 oacc = zero4();
            #pragma unroll
            for (int kc = 0; kc < 4; kc++) {
                bf16x8 pf = *(const bf16x8*)&Pw[l15*136 + kc*32 + lg*8];
                bf16x8 vf = *(const bf16x8*)&VT[dl*128 + ((kc*32 + lg*8) ^ xr)];
                oacc = bmfma(pf, vf, oacc);
            }
            #pragma unroll
            for (int r = 0; r < 4; r++) {
                int row = rt*16 + lg*4 + r;
                if (row < 98)
                    aout[((size_t)b_*98 + row)*192 + head*32 + dt*16 + l15] = (bf16)oacc[r];
            }
        }
        qf = qnext;
    }
}

// K5: window reverse + roll-back + residual(x) + LN2. grid = 1792
// (half-width split: 28 tokens/block, 21.6KB LDS -> ~7 blocks/CU).
// x1 out bf16 (LN2 stats still f32 from the LDS tile).
__global__ __launch_bounds__(256) void rev_res_ln2_k(
    const float* __restrict__ x, const float* __restrict__ pw,
    const float* __restrict__ g2, const float* __restrict__ b2,
    bf16* __restrict__ x1, bf16* __restrict__ xn2)
{
    __shared__ float tile[28*193];
    __shared__ float mu[28], rs[28];
    int blk = blockIdx.x;
    int bb = blk / 896; int r = blk % 896;
    int t = r / 112; int rem = r % 112;
    int h = rem >> 1, half = rem & 1;
    int ts = (t + 7) & 7;
    int hs = h - 3; if (hs < 0) hs += 56;
    int tid = threadIdx.x;
    const float* xs = x + ((size_t)bb*1536 + t)*3136 + h*56;
    for (int e = tid; e < 192*28; e += 256) {
        int c = e / 28, wi = e % 28;
        int w = half*28 + wi;
        tile[wi*193 + c] = xs[(size_t)c*25088 + w];
    }
    __syncthreads();
    int tb = ts >> 1, wt = ts & 1, hb = hs / 7, wh = hs % 7;
    for (int e = tid; e < 28*192; e += 256) {
        int wi = e / 192, c = e % 192;
        int w = half*28 + wi;
        int wsp = w - 3; if (wsp < 0) wsp += 56;
        int wb = wsp / 7, ww = wsp % 7;
        size_t tok = (size_t)(bb*256 + tb*64 + hb*8 + wb)*98 + wt*49 + wh*7 + ww;
        tile[wi*193 + c] += pw[tok*192 + c];
    }
    __syncthreads();
    if (tid < 112) {
        int row = tid >> 2, q = tid & 3;
        float s = 0.f, s2 = 0.f;
        for (int c = q*48; c < q*48 + 48; c++) {
            float v = tile[row*193 + c]; s += v; s2 += v*v;
        }
        s  += __shfl_xor(s, 1);  s  += __shfl_xor(s, 2);
        s2 += __shfl_xor(s2, 1); s2 += __shfl_xor(s2, 2);
        if (q == 0) {
            float m = s * (1.0f/192.0f);
            mu[row] = m;
            rs[row] = rsqrtf(s2 * (1.0f/192.0f) - m*m + 1e-5f);
        }
    }
    __syncthreads();
    size_t tok0 = ((size_t)(bb*8 + t)*56 + h)*56;
    for (int e = tid; e < 28*192; e += 256) {
        int wi = e / 192, c = e % 192;
        int w = half*28 + wi;
        float v = tile[wi*193 + c];
        x1[(tok0 + w)*192 + c] = (bf16)v;
        xn2[(tok0 + w)*192 + c] = (bf16)((v - mu[wi]) * rs[wi] * g2[c] + b2[c]);
    }
}

// ---------------------------------------------------------------------------
extern "C" void kernel_launch(void* const* d_in, const int* in_sizes, int n_in,
                              void* d_out, int out_size, void* d_ws, size_t ws_size,
                              hipStream_t stream)
{
    const float* x     = (const float*)d_in[0];
    const float* maskm = (const float*)d_in[1];
    const float* n1g   = (const float*)d_in[2];
    const float* n1b   = (const float*)d_in[3];
    const float* qkvw  = (const float*)d_in[4];
    const float* qkvb  = (const float*)d_in[5];
    const float* projw = (const float*)d_in[6];
    const float* projb = (const float*)d_in[7];
    const float* rpb   = (const float*)d_in[8];
    const float* n2g   = (const float*)d_in[9];
    const float* n2b   = (const float*)d_in[10];
    const float* f1w   = (const float*)d_in[11];
    const float* f1b   = (const float*)d_in[12];
    const float* f2w   = (const float*)d_in[13];
    const float* f2b   = (const float*)d_in[14];

    char* ws = (char*)d_ws;
    bf16*  qkv_wt  = (bf16*)(ws + 0);          // 221184
    bf16*  proj_wt = (bf16*)(ws + 221184);     // 73728
    bf16*  fc1_wt  = (bf16*)(ws + 294912);     // 294912
    bf16*  fc2_wt  = (bf16*)(ws + 589824);     // 294912
    float* biasF   = (float*)(ws + 884736);    // 294912
    // region A: xw (bf16, 19.27MB) -> reused as attn_out
    bf16* xw   = (bf16*)(ws + 1179648);
    bf16* aout = xw;
    // region B: qkv (bf16, 57.8MB, permuted layout) -> reused as proj-out f32
    char* Bp = ws + 1179648 + 19267584;
    bf16*  qkv  = (bf16*)Bp;
    float* pwin = (float*)Bp;
    // region C: x1 bf16; region D: xn2 bf16; region E: h1 bf16 / maskF f32
    char* Cp = Bp + 57802752;
    bf16*  x1  = (bf16*)Cp;
    bf16*  xn2 = (bf16*)(Cp + 19267584);
    bf16*  h1  = (bf16*)(Cp + 19267584 + 19267584);
    // maskF (12.85MB) aliases h1: read only during attn, h1 written by fc1
    // strictly after attn completes.
    float* maskF = (float*)(Cp + 19267584 + 19267584);

    prep_all_k<<<3786, 256, 0, stream>>>(qkvw, projw, f1w, f2w, rpb, maskm,
                                         qkv_wt, proj_wt, fc1_wt, fc2_wt,
                                         biasF, maskF);
    ln1_window_k<<<1792, 256, 0, stream>>>(x, n1g, n1b, xw);
    gemm_k<64, 192, 576, 192, 5, 0><<<784*3, 256, 0, stream>>>(xw, qkv_wt, qkvb, nullptr, qkv);
    attn_k<<<3072, 256, 0, stream>>>(qkv, biasF, maskF, aout);
    gemm_k<64, 192, 192, 64, 1, 0><<<784*3, 256, 0, stream>>>(aout, proj_wt, projb, nullptr, pwin);
    rev_res_ln2_k<<<1792, 256, 0, stream>>>(x, pwin, n2g, n2b, x1, xn2);
    gemm_k<64, 192, 768, 64, 2, 0><<<784*12, 256, 0, stream>>>(xn2, fc1_wt, f1b, nullptr, h1);
    gemm_k<128, 768, 192, 64, 4, 1><<<392*3, 256, 0, stream>>>(h1, fc2_wt, f2b, x1, (float*)d_out);
}

// Round 28
// 207.104 us; speedup vs baseline: 1.0588x; 1.0072x over previous
//
#include <hip/hip_runtime.h>
#include <hip/hip_bf16.h>
#include <math.h>

#define DEV __device__ __forceinline__

typedef __bf16 bf16;
typedef __bf16 bf16x8 __attribute__((ext_vector_type(8)));
typedef float f32x4 __attribute__((ext_vector_type(4)));

DEV f32x4 zero4() { f32x4 z; z[0]=0.f; z[1]=0.f; z[2]=0.f; z[3]=0.f; return z; }

DEV void gload_lds16(const bf16* g, bf16* l) {
    __builtin_amdgcn_global_load_lds(
        (const __attribute__((address_space(1))) void*)g,
        (__attribute__((address_space(3))) void*)l, 16, 0, 0);
}

// sigmoid-form GELU: v * sigmoid(1.702 v). 5 VALU ops.
DEV float gelu_f(float v) {
    float e = __expf(-1.702f * v);
    return v * __builtin_amdgcn_rcpf(1.0f + e);
}

DEV f32x4 bmfma(bf16x8 a, bf16x8 b, f32x4 c) {
    return __builtin_amdgcn_mfma_f32_16x16x32_bf16(a, b, c, 0, 0, 0);
}

// ---------------------------------------------------------------------------
// Geometry: B=2, C=192, T=8, H=56, W=56; window (2,7,7) N=98; shift (1,3,3)
// windows: 4*8*8=256 per batch, B_=512; tokens M = 50176
// qkv buffer layout (EPI=5 output): [b_][head][sel(q,k,v)][n=98][d=32]
// ---------------------------------------------------------------------------

// K0 (merged preps): blocks [0,3136) -> maskF, [3136,3712) -> weights,
// [3712,3786) -> biasF.
__global__ __launch_bounds__(256) void prep_all_k(
    const float* __restrict__ qw, const float* __restrict__ pw,
    const float* __restrict__ f1, const float* __restrict__ f2,
    const float* __restrict__ rpb, const float* __restrict__ maskm,
    bf16* __restrict__ qwt, bf16* __restrict__ pwt,
    bf16* __restrict__ f1t, bf16* __restrict__ f2t,
    float* __restrict__ biasF, float* __restrict__ maskF)
{
    int bid = blockIdx.x;
    if (bid < 3136) {
        int i = bid * 256 + threadIdx.x;   // (wib,rt,j,lane)
        if (i >= 256*7*7*64) return;
        int lane = i & 63; int g = i >> 6;
        int j = g % 7; g /= 7; int rt = g % 7; int wib = g / 7;
        int l15 = lane & 15, lg = lane >> 4;
        int nk = j*16 + l15;
        f32x4 o;
        #pragma unroll
        for (int r = 0; r < 4; r++) {
            int nq = rt*16 + lg*4 + r; if (nq > 97) nq = 97;
            o[r] = (nk < 98) ? maskm[((size_t)wib*98 + nq)*98 + nk] : 0.f;
        }
        *(f32x4*)&maskF[(size_t)i*4] = o;
    } else if (bid < 3712) {
        int i = (bid - 3136) * 256 + threadIdx.x;
        if (i < 576*192) { int n = i / 192, k = i % 192; qwt[i] = (bf16)qw[(size_t)k*576 + n]; }
        if (i < 192*192) { int n = i / 192, k = i % 192; pwt[i] = (bf16)pw[(size_t)k*192 + n]; }
        if (i < 768*192) { int n = i / 192, k = i % 192; f1t[i] = (bf16)f1[(size_t)k*768 + n]; }
        if (i < 192*768) { int n = i / 768, k = i % 768; f2t[i] = (bf16)f2[(size_t)k*192 + n]; }
    } else {
        int i = (bid - 3712) * 256 + threadIdx.x;   // (head,rt,j,lane)
        if (i >= 6*7*7*64) return;
        int lane = i & 63; int g = i >> 6;
        int j = g % 7; g /= 7; int rt = g % 7; int head = g / 7;
        int l15 = lane & 15, lg = lane >> 4;
        int nk = j*16 + l15;
        f32x4 o;
        #pragma unroll
        for (int r = 0; r < 4; r++) {
            int nq = rt*16 + lg*4 + r; if (nq > 97) nq = 97;
            if (nk < 98) {
                int t1 = nq/49, r1 = nq%49, h1 = r1/7, w1 = r1%7;
                int t2 = nk/49, r2 = nk%49, h2 = r2/7, w2 = r2%7;
                int idx = (t1 - t2 + 1)*169 + (h1 - h2 + 6)*13 + (w1 - w2 + 6);
                o[r] = rpb[idx*6 + head];
            } else {
                o[r] = -1e30f;
            }
        }
        *(f32x4*)&biasF[(size_t)i*4] = o;
    }
}

// K1: LN1 + cyclic shift + window partition. grid = B*T*H*2 = 1792
// (half-width split: 28 tokens/block, 21.6KB LDS -> ~7 blocks/CU).
__global__ __launch_bounds__(256) void ln1_window_k(
    const float* __restrict__ x, const float* __restrict__ g,
    const float* __restrict__ bta, bf16* __restrict__ xw)
{
    __shared__ float tile[28*193];
    __shared__ float mu[28], rs[28];
    int blk = blockIdx.x;
    int bb = blk / 896; int r = blk % 896;
    int ts = r / 112; int rem = r % 112;
    int hs = rem >> 1, half = rem & 1;
    int t = (ts + 1) & 7;
    int h = hs + 3; if (h >= 56) h -= 56;
    int tid = threadIdx.x;
    const float* xs = x + ((size_t)bb*1536 + t)*3136 + h*56;
    for (int e = tid; e < 192*28; e += 256) {
        int c = e / 28, wi = e % 28;
        int w = half*28 + wi + 3; if (w >= 56) w -= 56;
        tile[wi*193 + c] = xs[(size_t)c*25088 + w];
    }
    __syncthreads();
    if (tid < 112) {
        int row = tid >> 2, q = tid & 3;
        float s = 0.f, s2 = 0.f;
        for (int c = q*48; c < q*48 + 48; c++) {
            float v = tile[row*193 + c]; s += v; s2 += v*v;
        }
        s  += __shfl_xor(s, 1);  s  += __shfl_xor(s, 2);
        s2 += __shfl_xor(s2, 1); s2 += __shfl_xor(s2, 2);
        if (q == 0) {
            float m = s * (1.0f/192.0f);
            mu[row] = m;
            rs[row] = rsqrtf(s2 * (1.0f/192.0f) - m*m + 1e-5f);
        }
    }
    __syncthreads();
    int tb = ts >> 1, wt = ts & 1;
    int hb = hs / 7, wh = hs % 7;
    for (int e = tid; e < 28*192; e += 256) {
        int wi = e / 192, c = e % 192;
        int wsp = half*28 + wi;
        float v = (tile[wi*193 + c] - mu[wi]) * rs[wi] * g[c] + bta[c];
        int wb = wsp / 7, ww = wsp % 7;
        int widx = bb*256 + tb*64 + hb*8 + wb;
        int n = wt*49 + wh*7 + ww;
        xw[((size_t)widx*98 + n)*192 + c] = (bf16)v;
    }
}

// Generic bf16 MFMA GEMM: BM/BN templated, XCD-affinity strip swizzle,
// single- (DB=0) or double-buffered (DB=1) staging.
// EPI: 1 f32 direct; 2 gelu bf16 via LDS transpose;
//      4 bf16-resid add + channel-first f32x4 -> d_out;
//      5 bf16 permuted store [b_][head][sel][98][32] (attn-coalesced).
template<int BM, int KT, int NT, int BN, int EPI, int DB>
__global__ __launch_bounds__(256) void gemm_k(
    const bf16* __restrict__ A, const bf16* __restrict__ BT,
    const float* __restrict__ bias, const void* __restrict__ resid,
    void* __restrict__ outp)
{
    constexpr int BUFS = DB ? 2 : 1;
    __shared__ bf16 smem[BUFS*BM*64 + BUFS*BN*64];
    bf16* laB = smem;
    bf16* lbB = smem + BUFS*BM*64;
    constexpr int NTILES = NT / BN;
    constexpr int NK = KT / 64;
    constexpr int JT = BN / 32;            // j-tiles per wave
    constexpr int IT = BM / 32;            // i-tiles per wave
    constexpr int WM = BM / 2;             // wave row extent
    constexpr int WN = BN / 2;             // wave col extent
    constexpr int NM = 50176 / BM;         // M strips
    constexpr int SPX = NM / 8;            // strips per XCD (bijective)
    int blk = blockIdx.x;
    int xcd = blk & 7, ix = blk >> 3;
    int m0 = (xcd * SPX + ix / NTILES) * BM;
    int n0 = (ix % NTILES) * BN;
    int tid = threadIdx.x;
    int lane = tid & 63;
    int wv = tid >> 6;
    int wr = wv >> 1, wc = wv & 1;
    int l15 = lane & 15, lg = lane >> 4;

    auto stage = [&](int kt, int buf) {
        int kb = kt * 64;
        #pragma unroll
        for (int t = 0; t < BM/32; t++) {
            int e = t*256 + wv*64 + lane;
            int row = e >> 3, ck = e & 7;
            gload_lds16(&A[(size_t)(m0 + row)*KT + kb + ((ck ^ (row & 7)) << 3)],
                        &laB[buf*BM*64 + (t*256 + wv*64) * 8]);
        }
        #pragma unroll
        for (int t = 0; t < JT; t++) {
            int e = t*256 + wv*64 + lane;
            int row = e >> 3, ck = e & 7;
            gload_lds16(&BT[(size_t)(n0 + row)*KT + kb + ((ck ^ (row & 7)) << 3)],
                        &lbB[buf*BN*64 + (t*256 + wv*64) * 8]);
        }
    };

    f32x4 acc[IT][JT];
    #pragma unroll
    for (int i = 0; i < IT; i++)
        #pragma unroll
        for (int j = 0; j < JT; j++) acc[i][j] = zero4();

    auto compute = [&](int cur) {
        const bf16* lab = laB + cur*BM*64;
        const bf16* lbb = lbB + cur*BN*64;
        #pragma unroll
        for (int ks = 0; ks < 64; ks += 32) {
            int lc = (ks >> 3) + lg;
            bf16x8 af[IT], bfr[JT];
            #pragma unroll
            for (int i = 0; i < IT; i++) {
                int ri = wr*WM + i*16 + l15;
                af[i] = *(const bf16x8*)&lab[ri*64 + ((lc ^ (ri & 7)) << 3)];
            }
            #pragma unroll
            for (int j = 0; j < JT; j++) {
                int rj = wc*WN + j*16 + l15;
                bfr[j] = *(const bf16x8*)&lbb[rj*64 + ((lc ^ (rj & 7)) << 3)];
            }
            #pragma unroll
            for (int i = 0; i < IT; i++)
                #pragma unroll
                for (int j = 0; j < JT; j++)
                    acc[i][j] = bmfma(af[i], bfr[j], acc[i][j]);
        }
    };

    if constexpr (DB) {
        stage(0, 0);
        __syncthreads();
        for (int kt = 0; kt < NK; kt++) {
            int cur = kt & 1;
            if (kt + 1 < NK) stage(kt + 1, cur ^ 1);
            compute(cur);
            __syncthreads();
        }
    } else {
        for (int kt = 0; kt < NK; kt++) {
            stage(kt, 0);
            __syncthreads();
            compute(0);
            __syncthreads();
        }
    }

    if constexpr (EPI == 4) {
        const bf16* rs = (const bf16*)resid;
        #pragma unroll
        for (int i = 0; i < IT; i++) {
            #pragma unroll
            for (int j = 0; j < JT; j++) {
                int row0 = m0 + wr*WM + i*16 + lg*4;
                int col = n0 + wc*WN + j*16 + l15;
                f32x4 o;
                #pragma unroll
                for (int r = 0; r < 4; r++)
                    o[r] = acc[i][j][r] + bias[col] + (float)rs[(size_t)(row0 + r)*NT + col];
                int bb2 = row0 >= 25088;
                size_t off = (size_t)bb2*192*25088 + (size_t)col*25088 + (row0 - bb2*25088);
                *(f32x4*)&((float*)outp)[off] = o;
            }
        }
    } else if constexpr (EPI == 5) {
        #pragma unroll
        for (int i = 0; i < IT; i++) {
            #pragma unroll
            for (int j = 0; j < JT; j++) {
                int col = n0 + wc*WN + j*16 + l15;
                int sel = col / 192, hd = (col % 192) >> 5, d = col & 31;
                float bv = bias[col];
                #pragma unroll
                for (int r = 0; r < 4; r++) {
                    int row = m0 + wr*WM + i*16 + lg*4 + r;
                    int b_ = row / 98, n = row - b_*98;
                    size_t dst = (((size_t)b_*6 + hd)*3 + sel)*3136 + n*32 + d;
                    ((bf16*)outp)[dst] = (bf16)(acc[i][j][r] + bv);
                }
            }
        }
    } else if constexpr (EPI == 1) {
        #pragma unroll
        for (int i = 0; i < IT; i++) {
            #pragma unroll
            for (int j = 0; j < JT; j++) {
                #pragma unroll
                for (int r = 0; r < 4; r++) {
                    int row = m0 + wr*WM + i*16 + lg*4 + r;
                    int col = n0 + wc*WN + j*16 + l15;
                    ((float*)outp)[(size_t)row*NT + col] = acc[i][j][r] + bias[col];
                }
            }
        }
    } else {
        // EPI==2: gelu -> bf16 LDS transpose ([BM][72]) -> 16B stores.
        bf16* fs = smem;
        #pragma unroll
        for (int i = 0; i < IT; i++) {
            #pragma unroll
            for (int j = 0; j < JT; j++) {
                int colw = wc*WN + j*16 + l15;
                float bv = bias[n0 + colw];
                #pragma unroll
                for (int r = 0; r < 4; r++) {
                    int lr = wr*WM + i*16 + lg*4 + r;
                    fs[lr*72 + colw] = (bf16)gelu_f(acc[i][j][r] + bv);
                }
            }
        }
        __syncthreads();
        {
            constexpr int EPT = BM / 4;        // elems per thread
            constexpr int TPR = 64 / EPT;      // threads per row
            int lr = tid / TPR, c0 = (tid % TPR) * EPT;
            size_t gbase = (size_t)(m0 + lr)*NT + n0 + c0;
            #pragma unroll
            for (int k = 0; k < EPT/8; k++) {
                bf16x8 o = *(const bf16x8*)&fs[lr*72 + c0 + k*8];
                *(bf16x8*)&((bf16*)outp)[gbase + k*8] = o;
            }
        }
    }
}

// K3: attention, one block per (WINDOW, HEAD). grid 3072, block 256 (4 waves).
// Wave wv handles rt in {2wv, 2wv+1} (wave 3: rt 6 only). Pl has 4 per-wave
// buffers (LDS 25.4KB). VT staged with clamped source rows (keys>=98 hold
// V[97]; their P is exactly 0 via the -1e30 bias).
__global__ __launch_bounds__(256) void attn_k(
    const bf16* __restrict__ qkv, const float* __restrict__ biasF,
    const float* __restrict__ maskF, bf16* __restrict__ aout)
{
    __shared__ bf16 VT[32*128];
    __shared__ bf16 Pl[4*16*136];
    int blk = blockIdx.x;
    int t8 = (blk & 7) * 384 + (blk >> 3);
    int b_ = t8 / 6, head = t8 % 6;
    int tid = threadIdx.x, lane = tid & 63, wv = tid >> 6;
    int l15 = lane & 15, lg = (lane >> 4) & 3;
    int wib = b_ & 255;
    const bf16* base = qkv + (size_t)(b_*6 + head)*3*3136;

    {
        // Pl pad cols (112..127) zero for 4 wave-buffers + full VT stage
        unsigned int* pz = (unsigned int*)Pl;
        for (int e = tid; e < 512; e += 256) {
            int w2 = e >> 7, rem = e & 127;
            int row = rem >> 3, cp = rem & 7;
            pz[(w2*16 + row)*68 + 56 + cp] = 0u;
        }
        int dq = tid >> 6;               // d-octet 0..3
        int kl = tid & 63;
        const bf16* vbase = base + 2*3136 + dq*8;
        #pragma unroll
        for (int kr = 0; kr < 2; kr++) {
            int k = kr*64 + kl;
            int ks = k > 97 ? 97 : k;
            bf16x8 v8 = *(const bf16x8*)&vbase[ks*32];
            #pragma unroll
            for (int j = 0; j < 8; j++)
                VT[(dq*8 + j)*128 + (k ^ (j << 3))] = v8[j];
        }
    }
    __syncthreads();

    bf16x8 kfr[7];
    #pragma unroll
    for (int j = 0; j < 7; j++) {
        int krow = j*16 + l15; if (krow > 97) krow = 97;
        kfr[j] = *(const bf16x8*)&base[3136 + krow*32 + lg*8];
    }

    const float scale = 0.17677669529663687f;
    bf16* Pw = Pl + wv*16*136;
    const int rt0 = wv*2;
    const int rt1 = (wv*2 + 2 < 7) ? wv*2 + 2 : 7;

    auto loadQ = [&](int rt) {
        int qrow = rt*16 + l15; if (qrow > 97) qrow = 97;
        return *(const bf16x8*)&base[qrow*32 + lg*8];
    };
    bf16x8 qf = loadQ(rt0);

    #pragma unroll 1
    for (int rt = rt0; rt < rt1; rt++) {
        bf16x8 qnext = qf;
        if (rt + 1 < rt1) qnext = loadQ(rt + 1);
        f32x4 sacc[7];
        #pragma unroll
        for (int j = 0; j < 7; j++) sacc[j] = zero4();
        #pragma unroll
        for (int j = 0; j < 7; j++)
            sacc[j] = bmfma(qf, kfr[j], sacc[j]);
        {
            const float* bfp = biasF + ((size_t)(head*7 + rt)*7)*256 + lane*4;
            const float* mfp = maskF + ((size_t)(wib*7 + rt)*7)*256 + lane*4;
            #pragma unroll
            for (int j = 0; j < 7; j++) {
                f32x4 bv = *(const f32x4*)&bfp[j*256];
                f32x4 mv = *(const f32x4*)&mfp[j*256];
                sacc[j] = sacc[j]*scale + bv + mv;
            }
            f32x4 m4 = sacc[0];
            #pragma unroll
            for (int j = 1; j < 7; j++) {
                #pragma unroll
                for (int r = 0; r < 4; r++) m4[r] = fmaxf(m4[r], sacc[j][r]);
            }
            #pragma unroll
            for (int d = 1; d < 16; d <<= 1) {
                #pragma unroll
                for (int r = 0; r < 4; r++) m4[r] = fmaxf(m4[r], __shfl_xor(m4[r], d));
            }
            f32x4 s4 = zero4();
            #pragma unroll
            for (int j = 0; j < 7; j++) {
                #pragma unroll
                for (int r = 0; r < 4; r++) sacc[j][r] = __expf(sacc[j][r] - m4[r]);
                s4 += sacc[j];
            }
            #pragma unroll
            for (int d = 1; d < 16; d <<= 1) {
                #pragma unroll
                for (int r = 0; r < 4; r++) s4[r] += __shfl_xor(s4[r], d);
            }
            f32x4 inv4;
            #pragma unroll
            for (int r = 0; r < 4; r++) inv4[r] = 1.0f / s4[r];
            #pragma unroll
            for (int j = 0; j < 7; j++)
                #pragma unroll
                for (int r = 0; r < 4; r++)
                    Pw[(lg*4 + r)*136 + j*16 + l15] = (bf16)(sacc[j][r]*inv4[r]);
        }
        #pragma unroll
        for (int dt = 0; dt < 2; dt++) {
            int dl = dt*16 + l15;
            int xr = (dl & 7) << 3;
            f32x4 oacc = zero4();
            #pragma unroll
            for (int kc = 0; kc < 4; kc++) {
                bf16x8 pf = *(const bf16x8*)&Pw[l15*136 + kc*32 + lg*8];
                bf16x8 vf = *(const bf16x8*)&VT[dl*128 + ((kc*32 + lg*8) ^ xr)];
                oacc = bmfma(pf, vf, oacc);
            }
            #pragma unroll
            for (int r = 0; r < 4; r++) {
                int row = rt*16 + lg*4 + r;
                if (row < 98)
                    aout[((size_t)b_*98 + row)*192 + head*32 + dt*16 + l15] = (bf16)oacc[r];
            }
        }
        qf = qnext;
    }
}

// K5: window reverse + roll-back + residual(x) + LN2. grid = 1792
// (half-width split: 28 tokens/block, 21.6KB LDS -> ~7 blocks/CU).
// x1 out bf16 (LN2 stats still f32 from the LDS tile).
__global__ __launch_bounds__(256) void rev_res_ln2_k(
    const float* __restrict__ x, const float* __restrict__ pw,
    const float* __restrict__ g2, const float* __restrict__ b2,
    bf16* __restrict__ x1, bf16* __restrict__ xn2)
{
    __shared__ float tile[28*193];
    __shared__ float mu[28], rs[28];
    int blk = blockIdx.x;
    int bb = blk / 896; int r = blk % 896;
    int t = r / 224; int rem = r % 224;
    int h = rem >> 2, q2 = rem & 3;
    // NOTE: keep exact r27 decomposition (rem>>1 half split)
    h = (r % 112) >> 1; int half = (r % 112) & 1; t = (r / 112);
    int ts = (t + 7) & 7;
    int hs = h - 3; if (hs < 0) hs += 56;
    int tid = threadIdx.x;
    const float* xs = x + ((size_t)bb*1536 + t)*3136 + h*56;
    for (int e = tid; e < 192*28; e += 256) {
        int c = e / 28, wi = e % 28;
        int w = half*28 + wi;
        tile[wi*193 + c] = xs[(size_t)c*25088 + w];
    }
    __syncthreads();
    int tb = ts >> 1, wt = ts & 1, hb = hs / 7, wh = hs % 7;
    for (int e = tid; e < 28*192; e += 256) {
        int wi = e / 192, c = e % 192;
        int w = half*28 + wi;
        int wsp = w - 3; if (wsp < 0) wsp += 56;
        int wb = wsp / 7, ww = wsp % 7;
        size_t tok = (size_t)(bb*256 + tb*64 + hb*8 + wb)*98 + wt*49 + wh*7 + ww;
        tile[wi*193 + c] += pw[tok*192 + c];
    }
    __syncthreads();
    if (tid < 112) {
        int row = tid >> 2, q = tid & 3;
        float s = 0.f, s2 = 0.f;
        for (int c = q*48; c < q*48 + 48; c++) {
            float v = tile[row*193 + c]; s += v; s2 += v*v;
        }
        s  += __shfl_xor(s, 1);  s  += __shfl_xor(s, 2);
        s2 += __shfl_xor(s2, 1); s2 += __shfl_xor(s2, 2);
        if (q == 0) {
            float m = s * (1.0f/192.0f);
            mu[row] = m;
            rs[row] = rsqrtf(s2 * (1.0f/192.0f) - m*m + 1e-5f);
        }
    }
    __syncthreads();
    size_t tok0 = ((size_t)(bb*8 + t)*56 + h)*56;
    for (int e = tid; e < 28*192; e += 256) {
        int wi = e / 192, c = e % 192;
        int w = half*28 + wi;
        float v = tile[wi*193 + c];
        x1[(tok0 + w)*192 + c] = (bf16)v;
        xn2[(tok0 + w)*192 + c] = (bf16)((v - mu[wi]) * rs[wi] * g2[c] + b2[c]);
    }
}

// ---------------------------------------------------------------------------
extern "C" void kernel_launch(void* const* d_in, const int* in_sizes, int n_in,
                              void* d_out, int out_size, void* d_ws, size_t ws_size,
                              hipStream_t stream)
{
    const float* x     = (const float*)d_in[0];
    const float* maskm = (const float*)d_in[1];
    const float* n1g   = (const float*)d_in[2];
    const float* n1b   = (const float*)d_in[3];
    const float* qkvw  = (const float*)d_in[4];
    const float* qkvb  = (const float*)d_in[5];
    const float* projw = (const float*)d_in[6];
    const float* projb = (const float*)d_in[7];
    const float* rpb   = (const float*)d_in[8];
    const float* n2g   = (const float*)d_in[9];
    const float* n2b   = (const float*)d_in[10];
    const float* f1w   = (const float*)d_in[11];
    const float* f1b   = (const float*)d_in[12];
    const float* f2w   = (const float*)d_in[13];
    const float* f2b   = (const float*)d_in[14];

    char* ws = (char*)d_ws;
    bf16*  qkv_wt  = (bf16*)(ws + 0);          // 221184
    bf16*  proj_wt = (bf16*)(ws + 221184);     // 73728
    bf16*  fc1_wt  = (bf16*)(ws + 294912);     // 294912
    bf16*  fc2_wt  = (bf16*)(ws + 589824);     // 294912
    float* biasF   = (float*)(ws + 884736);    // 294912
    // region A: xw (bf16, 19.27MB) -> reused as attn_out
    bf16* xw   = (bf16*)(ws + 1179648);
    bf16* aout = xw;
    // region B: qkv (bf16, 57.8MB, permuted layout) -> reused as proj-out f32
    char* Bp = ws + 1179648 + 19267584;
    bf16*  qkv  = (bf16*)Bp;
    float* pwin = (float*)Bp;
    // region C: x1 bf16; region D: xn2 bf16; region E: h1 bf16 / maskF f32
    char* Cp = Bp + 57802752;
    bf16*  x1  = (bf16*)Cp;
    bf16*  xn2 = (bf16*)(Cp + 19267584);
    bf16*  h1  = (bf16*)(Cp + 19267584 + 19267584);
    // maskF (12.85MB) aliases h1: read only during attn, h1 written by fc1
    // strictly after attn completes.
    float* maskF = (float*)(Cp + 19267584 + 19267584);

    prep_all_k<<<3786, 256, 0, stream>>>(qkvw, projw, f1w, f2w, rpb, maskm,
                                         qkv_wt, proj_wt, fc1_wt, fc2_wt,
                                         biasF, maskF);
    ln1_window_k<<<1792, 256, 0, stream>>>(x, n1g, n1b, xw);
    gemm_k<64, 192, 576, 192, 5, 0><<<784*3, 256, 0, stream>>>(xw, qkv_wt, qkvb, nullptr, qkv);
    attn_k<<<3072, 256, 0, stream>>>(qkv, biasF, maskF, aout);
    gemm_k<64, 192, 192, 64, 1, 0><<<784*3, 256, 0, stream>>>(aout, proj_wt, projb, nullptr, pwin);
    rev_res_ln2_k<<<1792, 256, 0, stream>>>(x, pwin, n2g, n2b, x1, xn2);
    gemm_k<64, 192, 768, 64, 2, 0><<<784*12, 256, 0, stream>>>(xn2, fc1_wt, f1b, nullptr, h1);
    gemm_k<128, 768, 192, 64, 4, 1><<<392*3, 256, 0, stream>>>(h1, fc2_wt, f2b, x1, (float*)d_out);
}